// Round 8
// baseline (531.161 us; speedup 1.0000x reference)
//
#include <hip/hip_runtime.h>
#include <hip/hip_bf16.h>
#include <cstdint>
#include <cstddef>

using fx4  = __attribute__((ext_vector_type(4))) float;
using bfx8 = __attribute__((ext_vector_type(8))) short;
using sx4  = __attribute__((ext_vector_type(4))) short;

#define DEV __device__ __forceinline__

static constexpr int BATCH = 64;
static constexpr int NTOK  = 197;
static constexpr int NH    = 12;
static constexpr int HD    = 64;
static constexpr int MROWS = BATCH * NTOK;   // 12608
static constexpr int MPAD  = 12800;          // 50 * 256 (also covers 99*128)
static constexpr int KDIM  = 768;

DEV unsigned short f2bf(float f) {
  unsigned u = __builtin_bit_cast(unsigned, f);
  u += 0x7FFFu + ((u >> 16) & 1u);
  return (unsigned short)(u >> 16);
}
DEV float bf2f(unsigned short s) {
  unsigned u = ((unsigned)s) << 16;
  return __builtin_bit_cast(float, u);
}
DEV void split2(float x, short &hi, short &lo) {
  unsigned short h = f2bf(x);
  float r = x - bf2f(h);
  hi = (short)h;
  lo = (short)f2bf(r);
}

DEV void gload16(const unsigned short* g, unsigned short* l) {
  __builtin_amdgcn_global_load_lds(
      (const __attribute__((address_space(1))) unsigned int*)g,
      (__attribute__((address_space(3))) unsigned int*)l, 16, 0, 0);
}

// ---------------------------------------------------------------------------
// rpb[h][i][j] = rpb_high[h_index[i,j], h] + rpb_width[w_index[i,j], h]
// ---------------------------------------------------------------------------
__global__ void rpb_kernel(const float* __restrict__ rh, const float* __restrict__ rw,
                           const int* __restrict__ hidx, const int* __restrict__ widx,
                           float* __restrict__ rpb)
{
  int e = blockIdx.x * 256 + threadIdx.x;
  const int NN = NTOK * NTOK;
  if (e >= NH * NN) return;
  int h = e / NN, ij = e % NN;
  rpb[e] = rh[hidx[ij] * NH + h] + rw[widx[ij] * NH + h];
}

// ---------------------------------------------------------------------------
// Elementwise fp32 -> (hi, lo) bf16 planes. Pads [nvec, nvec_pad) with zeros.
// ---------------------------------------------------------------------------
__global__ void split_kernel(const float* __restrict__ in,
                             unsigned short* __restrict__ hi,
                             unsigned short* __restrict__ lo,
                             int nvec, int nvec_pad)
{
  for (int v = blockIdx.x * 256 + threadIdx.x; v < nvec_pad; v += gridDim.x * 256) {
    fx4 x = (v < nvec) ? ((const fx4*)in)[v] : fx4{0.f, 0.f, 0.f, 0.f};
    sx4 h4, l4;
    #pragma unroll
    for (int q = 0; q < 4; q++) {
      short hh, ll;
      split2(x[q], hh, ll);
      h4[q] = hh; l4[q] = ll;
    }
    ((sx4*)hi)[v] = h4;
    ((sx4*)lo)[v] = l4;
  }
}

// ---------------------------------------------------------------------------
// 256x256 split-bf16 MFMA GEMM (qkv): C = Ah.Bh^T + Ah.Bl^T + Al.Bh^T over
// K'=2304 (36 K-tiles of 64). 8 waves (2Mx4N), 128KB LDS double-buffer,
// global_load_lds staging with (row&7)-XOR granule swizzle (pre-swizzled
// source + swizzled read), raw s_barrier + counted vmcnt(8) pipeline.
// Epilogue: bias + scale, scatter q/k/v fp32 [B,H,N,hd].
// ---------------------------------------------------------------------------
__global__ __launch_bounds__(512, 2)
void gemm256_kernel(const unsigned short* __restrict__ Ah, const unsigned short* __restrict__ Al,
                    const unsigned short* __restrict__ Bh, const unsigned short* __restrict__ Bl,
                    const float* __restrict__ bias0, const float* __restrict__ bias1,
                    float* __restrict__ qf, float* __restrict__ kf,
                    float* __restrict__ vf)
{
  __shared__ unsigned short As[2][256 * 64];   // 32 KB each
  __shared__ unsigned short Bs[2][256 * 64];   // total 128 KB

  const int t  = threadIdx.x;
  const int w  = t >> 6, l = t & 63;
  const int wr = w >> 2, wc = w & 3;
  const int fr = l & 15, g = l >> 4;
  const int bm = blockIdx.x / 9, bn = blockIdx.x % 9;

  // staging geometry: granule = 16B; K-tile = 256 rows x 8 granules.
  // round rd, wave w, lane l -> LDS granule gidx = rd*512 + w*64 + l
  //   row = gidx>>3 = rd*64 + w*8 + (l>>3), lin col granule = l&7.
  // swizzled SOURCE granule = (l&7) ^ (row&7) = (l&7) ^ (l>>3).
  const int srow = w * 8 + (l >> 3);
  const int sgr8 = ((l & 7) ^ (l >> 3)) * 8;
  const size_t arow0 = (size_t)(bm * 256) + srow;
  const size_t brow0 = (size_t)(bn * 256) + srow;

  auto STAGE = [&](int ts, int c) {
    const int sp = ts / 12;                 // source phase 0,1,2
    const int k0 = (ts - sp * 12) * 64;
    const unsigned short* Ap = (sp < 2) ? Ah : Al;
    const unsigned short* Bp = (sp == 0) ? Bh : (sp == 1 ? Bl : Bh);
    const unsigned short* ag = Ap + arow0 * KDIM + k0 + sgr8;
    const unsigned short* bg = Bp + brow0 * KDIM + k0 + sgr8;
    unsigned short* al = &As[c][w * 64 * 8];
    unsigned short* bl = &Bs[c][w * 64 * 8];
    #pragma unroll
    for (int rd = 0; rd < 4; rd++) {
      gload16(ag + (size_t)rd * 64 * KDIM, al + rd * 512 * 8);
      gload16(bg + (size_t)rd * 64 * KDIM, bl + rd * 512 * 8);
    }
  };

  fx4 acc[8][4];
  #pragma unroll
  for (int i = 0; i < 8; i++)
    #pragma unroll
    for (int j = 0; j < 4; j++) acc[i][j] = fx4{0.f, 0.f, 0.f, 0.f};

  STAGE(0, 0);
  STAGE(1, 1);
  asm volatile("s_waitcnt vmcnt(8)" ::: "memory");
  __builtin_amdgcn_s_barrier();
  asm volatile("" ::: "memory");

  const int a_r0 = wr * 128 + fr;   // + i*16 ; (row&7)==(fr&7) since offsets %8==0
  const int b_r0 = wc * 64 + fr;    // + j*16
  const int swzg = fr & 7;

  #pragma unroll 1
  for (int tt = 0; tt < 36; tt++) {
    const int c = tt & 1;

    __builtin_amdgcn_s_setprio(1);
    #pragma unroll
    for (int ks = 0; ks < 2; ks++) {
      const int gsw = ((ks * 4 + g) ^ swzg) * 8;
      bfx8 fb[4];
      #pragma unroll
      for (int j = 0; j < 4; j++)
        fb[j] = *(const bfx8*)&Bs[c][(b_r0 + j * 16) * 64 + gsw];
      #pragma unroll
      for (int i = 0; i < 8; i++) {
        bfx8 fa = *(const bfx8*)&As[c][(a_r0 + i * 16) * 64 + gsw];
        #pragma unroll
        for (int j = 0; j < 4; j++)
          acc[i][j] = __builtin_amdgcn_mfma_f32_16x16x32_bf16(fa, fb[j], acc[i][j], 0, 0, 0);
      }
    }
    __builtin_amdgcn_s_setprio(0);

    asm volatile("s_waitcnt lgkmcnt(0)" ::: "memory");
    __builtin_amdgcn_s_barrier();          // all waves done reading buf c
    asm volatile("" ::: "memory");
    if (tt < 34) {
      STAGE(tt + 2, c);                    // overwrite buf c with K-tile tt+2
      asm volatile("s_waitcnt vmcnt(8)" ::: "memory");   // drain buf c^1 loads
    } else {
      asm volatile("s_waitcnt vmcnt(0)" ::: "memory");   // tail drain
    }
    __builtin_amdgcn_s_barrier();          // buf c^1 visible to all
    asm volatile("" ::: "memory");
  }

  // epilogue: frag (i,j): row = g*4+r, col = fr  (verified layout)
  #pragma unroll
  for (int i = 0; i < 8; i++) {
    #pragma unroll
    for (int j = 0; j < 4; j++) {
      #pragma unroll
      for (int r = 0; r < 4; r++) {
        int row = bm * 256 + wr * 128 + i * 16 + g * 4 + r;
        int col = bn * 256 + wc * 64 + j * 16 + fr;
        if (row >= MROWS) continue;
        float v = acc[i][j][r];
        int which = col / 768;
        int hh = (col >> 6) % 12;
        int d  = col & 63;
        int b  = row / NTOK, n = row % NTOK;
        size_t o = (((size_t)(b * NH + hh)) * NTOK + n) * HD + d;
        if (which == 0)      qf[o] = (v + bias0[col]) * 0.125f;
        else if (which == 1) kf[o] = v;
        else                 vf[o] = v + bias1[col - 1536];
      }
    }
  }
}

// ---------------------------------------------------------------------------
// 128x128 split-bf16 MFMA GEMM (kept for proj): C = Ah.Bh^T + Ah.Bl^T + Al.Bh^T
// MODE 1: proj epilogue (+bias -> out fp32)
// ---------------------------------------------------------------------------
template<int NT, int MODE>
__global__ __launch_bounds__(256, 2)
void gemm_bf16_kernel(const unsigned short* __restrict__ Ah, const unsigned short* __restrict__ Al,
                      const unsigned short* __restrict__ Bh, const unsigned short* __restrict__ Bl,
                      const float* __restrict__ bias0,
                      float* __restrict__ outp)
{
  __shared__ unsigned short At[128 * 32];
  __shared__ unsigned short Bt[128 * 32];

  const int t  = threadIdx.x;
  const int w  = t >> 6, l = t & 63;
  const int wr = w >> 1, wc = w & 1;
  const int fr = l & 15, g = l >> 4;
  const int bm = blockIdx.x / NT, bn = blockIdx.x % NT;

  const int r_issue = l >> 2;
  const int c_us    = (l & 3) * 8;

  fx4 acc[4][4];
  #pragma unroll
  for (int i = 0; i < 4; i++)
    #pragma unroll
    for (int j = 0; j < 4; j++) acc[i][j] = fx4{0.f, 0.f, 0.f, 0.f};

  #pragma unroll 1
  for (int kt = 0; kt < 72; kt++) {
    const int ph = kt / 24;
    const int k0 = (kt % 24) * 32;
    const unsigned short* Ap = (ph < 2) ? Ah : Al;
    const unsigned short* Bp = (ph == 0) ? Bh : (ph == 1 ? Bl : Bh);

    __syncthreads();
    #pragma unroll
    for (int e2 = 0; e2 < 2; e2++) {
      int e = w * 2 + e2;
      int arow = bm * 128 + e * 16 + r_issue;
      gload16(Ap + (size_t)arow * KDIM + k0 + c_us, &At[e * 512]);
      int brow = bn * 128 + e * 16 + r_issue;
      gload16(Bp + (size_t)brow * KDIM + k0 + c_us, &Bt[e * 512]);
    }
    __syncthreads();

    bfx8 fa[4], fb[4];
    #pragma unroll
    for (int i = 0; i < 4; i++)
      fa[i] = *(const bfx8*)&At[(wr * 64 + i * 16 + fr) * 32 + g * 8];
    #pragma unroll
    for (int j = 0; j < 4; j++)
      fb[j] = *(const bfx8*)&Bt[(wc * 64 + j * 16 + fr) * 32 + g * 8];
    #pragma unroll
    for (int i = 0; i < 4; i++)
      #pragma unroll
      for (int j = 0; j < 4; j++)
        acc[i][j] = __builtin_amdgcn_mfma_f32_16x16x32_bf16(fa[i], fb[j], acc[i][j], 0, 0, 0);
  }

  #pragma unroll
  for (int i = 0; i < 4; i++) {
    #pragma unroll
    for (int j = 0; j < 4; j++) {
      #pragma unroll
      for (int r = 0; r < 4; r++) {
        int row = bm * 128 + wr * 64 + i * 16 + g * 4 + r;
        int col = bn * 128 + wc * 64 + j * 16 + fr;
        if (row >= MROWS) continue;
        outp[(size_t)row * 768 + col] = acc[i][j][r] + bias0[col];
      }
    }
  }
}

// ---------------------------------------------------------------------------
// MFMA attention (verified round 7). Block = (b, h, qt); 4 waves.
// ---------------------------------------------------------------------------
__global__ __launch_bounds__(256)
void attn_mfma_kernel(const float* __restrict__ qf, const float* __restrict__ kf,
                      const float* __restrict__ vf, const float* __restrict__ rpb,
                      float* __restrict__ of)
{
  __shared__ union {
    struct { short Qb[64 * 72]; short Kb[224 * 72]; } s;
    struct { short Pb[64 * 232]; short Vt[64 * 232]; } p;
  } u;

  const int t  = threadIdx.x;
  const int w  = t >> 6, l = t & 63;
  const int fr = l & 15, g = l >> 4;
  const int bx = blockIdx.x;
  const int b  = bx / (NH * 4);
  const int h  = (bx / 4) % NH;
  const int qt = bx & 3;
  const size_t base = ((size_t)(b * NH + h)) * NTOK * HD;
  const float* qg = qf + base;
  const float* kg = kf + base;
  const float* vg = vf + base;
  const float* rhb = rpb + (size_t)h * (NTOK * NTOK);

  {
    const int rr = t >> 3, c8 = (t & 7) * 8;
    #pragma unroll
    for (int p = 0; p < 2; p++) {
      int r = p * 32 + rr;
      int qrow = qt * 64 + r;
      fx4 a0 = fx4{0.f,0.f,0.f,0.f}, a1 = fx4{0.f,0.f,0.f,0.f};
      if (qrow < NTOK) {
        a0 = *(const fx4*)(qg + (size_t)qrow * HD + c8);
        a1 = *(const fx4*)(qg + (size_t)qrow * HD + c8 + 4);
      }
      bfx8 o8;
      #pragma unroll
      for (int q2 = 0; q2 < 4; q2++) {
        o8[q2]     = (short)f2bf(a0[q2]);
        o8[q2 + 4] = (short)f2bf(a1[q2]);
      }
      *(bfx8*)&u.s.Qb[r * 72 + c8] = o8;
    }
    #pragma unroll
    for (int p = 0; p < 7; p++) {
      int r = p * 32 + rr;
      fx4 a0 = fx4{0.f,0.f,0.f,0.f}, a1 = fx4{0.f,0.f,0.f,0.f};
      if (r < NTOK) {
        a0 = *(const fx4*)(kg + (size_t)r * HD + c8);
        a1 = *(const fx4*)(kg + (size_t)r * HD + c8 + 4);
      }
      bfx8 o8;
      #pragma unroll
      for (int q2 = 0; q2 < 4; q2++) {
        o8[q2]     = (short)f2bf(a0[q2]);
        o8[q2 + 4] = (short)f2bf(a1[q2]);
      }
      *(bfx8*)&u.s.Kb[r * 72 + c8] = o8;
    }
  }
  __syncthreads();

  bfx8 aq0 = *(const bfx8*)&u.s.Qb[(w * 16 + fr) * 72 + g * 8];
  bfx8 aq1 = *(const bfx8*)&u.s.Qb[(w * 16 + fr) * 72 + 32 + g * 8];
  fx4 sc[14];
  #pragma unroll
  for (int j = 0; j < 14; j++) sc[j] = fx4{0.f, 0.f, 0.f, 0.f};
  #pragma unroll
  for (int j = 0; j < 14; j++) {
    bfx8 k0 = *(const bfx8*)&u.s.Kb[(j * 16 + fr) * 72 + g * 8];
    bfx8 k1 = *(const bfx8*)&u.s.Kb[(j * 16 + fr) * 72 + 32 + g * 8];
    sc[j] = __builtin_amdgcn_mfma_f32_16x16x32_bf16(aq0, k0, sc[j], 0, 0, 0);
    sc[j] = __builtin_amdgcn_mfma_f32_16x16x32_bf16(aq1, k1, sc[j], 0, 0, 0);
  }

  #pragma unroll
  for (int j = 0; j < 14; j++) {
    int key = j * 16 + fr;
    if (key < NTOK) {
      #pragma unroll
      for (int r = 0; r < 4; r++) {
        int qrow = qt * 64 + w * 16 + g * 4 + r;
        if (qrow < NTOK) sc[j][r] += rhb[qrow * NTOK + key];
      }
    } else {
      #pragma unroll
      for (int r = 0; r < 4; r++) sc[j][r] = -1e30f;
    }
  }

  float inv4[4];
  #pragma unroll
  for (int r = 0; r < 4; r++) {
    float m = sc[0][r];
    #pragma unroll
    for (int j = 1; j < 14; j++) m = fmaxf(m, sc[j][r]);
    #pragma unroll
    for (int off = 1; off < 16; off <<= 1) m = fmaxf(m, __shfl_xor(m, off));
    float sum = 0.f;
    #pragma unroll
    for (int j = 0; j < 14; j++) {
      float e = __expf(sc[j][r] - m);
      sc[j][r] = e; sum += e;
    }
    #pragma unroll
    for (int off = 1; off < 16; off <<= 1) sum += __shfl_xor(sum, off);
    inv4[r] = 1.0f / sum;
  }

  __syncthreads();

  #pragma unroll
  for (int j = 0; j < 14; j++) {
    int key = j * 16 + fr;
    #pragma unroll
    for (int r = 0; r < 4; r++)
      u.p.Pb[(w * 16 + g * 4 + r) * 232 + key] = (short)f2bf(sc[j][r]);
  }
  #pragma unroll
  for (int rep = 0; rep < 14; rep++) {
    int task = rep * 256 + t;
    int m = task >> 4, dg = task & 15;
    fx4 v = (m < NTOK) ? *(const fx4*)(vg + (size_t)m * HD + dg * 4)
                       : fx4{0.f, 0.f, 0.f, 0.f};
    #pragma unroll
    for (int q2 = 0; q2 < 4; q2++)
      u.p.Vt[(dg * 4 + q2) * 232 + m] = (short)f2bf(v[q2]);
  }
  __syncthreads();

  fx4 o2[4];
  #pragma unroll
  for (int j = 0; j < 4; j++) o2[j] = fx4{0.f, 0.f, 0.f, 0.f};
  #pragma unroll
  for (int kc = 0; kc < 7; kc++) {
    bfx8 pa = *(const bfx8*)&u.p.Pb[(w * 16 + fr) * 232 + kc * 32 + g * 8];
    #pragma unroll
    for (int j = 0; j < 4; j++) {
      bfx8 vb = *(const bfx8*)&u.p.Vt[(j * 16 + fr) * 232 + kc * 32 + g * 8];
      o2[j] = __builtin_amdgcn_mfma_f32_16x16x32_bf16(pa, vb, o2[j], 0, 0, 0);
    }
  }

  #pragma unroll
  for (int r = 0; r < 4; r++) {
    int qrow = qt * 64 + w * 16 + g * 4 + r;
    if (qrow < NTOK) {
      float inv = inv4[r];
      #pragma unroll
      for (int j = 0; j < 4; j++)
        of[((size_t)(b * NTOK + qrow)) * 768 + h * 64 + j * 16 + fr] = o2[j][r] * inv;
    }
  }
}

// ---------------------------------------------------------------------------
extern "C" void kernel_launch(void* const* d_in, const int* in_sizes, int n_in,
                              void* d_out, int out_size, void* d_ws, size_t ws_size,
                              hipStream_t stream)
{
  const float* x      = (const float*)d_in[0];
  const float* qkv_w  = (const float*)d_in[1];
  const float* q_bias = (const float*)d_in[2];
  const float* v_bias = (const float*)d_in[3];
  const float* proj_w = (const float*)d_in[4];
  const float* proj_b = (const float*)d_in[5];
  const float* rpb_h  = (const float*)d_in[6];
  const float* rpb_w  = (const float*)d_in[7];
  const int*   h_idx  = (const int*)d_in[8];
  const int*   w_idx  = (const int*)d_in[9];
  float* out = (float*)d_out;

  char* ws = (char*)d_ws;
  size_t off = 0;
  auto alloc = [&](size_t bytes) { size_t o = off; off += (bytes + 255) & ~(size_t)255; return o; };

  const size_t QKV_ELEMS = (size_t)BATCH * NH * NTOK * HD;
  unsigned short* Axh = (unsigned short*)(ws + alloc((size_t)MPAD * KDIM * 2));
  unsigned short* Axl = (unsigned short*)(ws + alloc((size_t)MPAD * KDIM * 2));
  unsigned short* Bqh = (unsigned short*)(ws + alloc((size_t)2304 * KDIM * 2));
  unsigned short* Bql = (unsigned short*)(ws + alloc((size_t)2304 * KDIM * 2));
  unsigned short* Bph = (unsigned short*)(ws + alloc((size_t)768 * KDIM * 2));
  unsigned short* Bpl = (unsigned short*)(ws + alloc((size_t)768 * KDIM * 2));
  float* qfp = (float*)(ws + alloc(QKV_ELEMS * 4));
  float* kfp = (float*)(ws + alloc(QKV_ELEMS * 4));
  float* vfp = (float*)(ws + alloc(QKV_ELEMS * 4));
  float* rpb = (float*)(ws + alloc((size_t)NH * NTOK * NTOK * 4));
  float* ofp = (float*)(ws + alloc((size_t)MROWS * KDIM * 4));
  (void)ws_size; (void)in_sizes; (void)n_in; (void)out_size;

  const int nvec_x  = MROWS * KDIM / 4;
  const int nvec_xp = MPAD * KDIM / 4;

  // 1) split inputs into bf16 hi/lo planes; rpb table
  split_kernel<<<2048, 256, 0, stream>>>(x, Axh, Axl, nvec_x, nvec_xp);
  split_kernel<<<1024, 256, 0, stream>>>(qkv_w, Bqh, Bql, 2304 * KDIM / 4, 2304 * KDIM / 4);
  split_kernel<<<512, 256, 0, stream>>>(proj_w, Bph, Bpl, 768 * KDIM / 4, 768 * KDIM / 4);
  {
    int total = NH * NTOK * NTOK;
    rpb_kernel<<<(total + 255) / 256, 256, 0, stream>>>(rpb_h, rpb_w, h_idx, w_idx, rpb);
  }
  // 2) qkv GEMM: 256x256 tiles, 50 x 9 grid, 512 threads
  gemm256_kernel<<<50 * 9, 512, 0, stream>>>(
      Axh, Axl, Bqh, Bql, q_bias, v_bias, qfp, kfp, vfp);
  // 3) MFMA attention
  attn_mfma_kernel<<<BATCH * NH * 4, 256, 0, stream>>>(qfp, kfp, vfp, rpb, ofp);
  // 4) split attention output, proj GEMM: 99 x 6 tiles (128x128)
  split_kernel<<<2048, 256, 0, stream>>>(ofp, Axh, Axl, nvec_x, nvec_xp);
  gemm_bf16_kernel<6, 1><<<99 * 6, 256, 0, stream>>>(
      Axh, Axl, Bph, Bpl, proj_b, out);
}

// Round 9
// 285.620 us; speedup vs baseline: 1.8597x; 1.8597x over previous
//
#include <hip/hip_runtime.h>
#include <hip/hip_bf16.h>
#include <cstdint>
#include <cstddef>

using fx4  = __attribute__((ext_vector_type(4))) float;
using bfx8 = __attribute__((ext_vector_type(8))) short;
using sx4  = __attribute__((ext_vector_type(4))) short;

#define DEV __device__ __forceinline__

static constexpr int BATCH = 64;
static constexpr int NTOK  = 197;
static constexpr int NH    = 12;
static constexpr int HD    = 64;
static constexpr int MROWS = BATCH * NTOK;   // 12608
static constexpr int MPAD  = 12800;          // covers 99*128 = 12672
static constexpr int KDIM  = 768;

DEV unsigned short f2bf(float f) {
  unsigned u = __builtin_bit_cast(unsigned, f);
  u += 0x7FFFu + ((u >> 16) & 1u);
  return (unsigned short)(u >> 16);
}

DEV void gload16(const unsigned short* g, unsigned short* l) {
  __builtin_amdgcn_global_load_lds(
      (const __attribute__((address_space(1))) unsigned int*)g,
      (__attribute__((address_space(3))) unsigned int*)l, 16, 0, 0);
}

// ---------------------------------------------------------------------------
// rpb[h][i][j] = rpb_high[h_index[i,j], h] + rpb_width[w_index[i,j], h]
// ---------------------------------------------------------------------------
__global__ void rpb_kernel(const float* __restrict__ rh, const float* __restrict__ rw,
                           const int* __restrict__ hidx, const int* __restrict__ widx,
                           float* __restrict__ rpb)
{
  int e = blockIdx.x * 256 + threadIdx.x;
  const int NN = NTOK * NTOK;
  if (e >= NH * NN) return;
  int h = e / NN, ij = e % NN;
  rpb[e] = rh[hidx[ij] * NH + h] + rw[widx[ij] * NH + h];
}

// ---------------------------------------------------------------------------
// Elementwise fp32 -> bf16. Pads [nvec, nvec_pad) with zeros. (fx4 granules)
// ---------------------------------------------------------------------------
__global__ void cvt_kernel(const float* __restrict__ in,
                           unsigned short* __restrict__ out,
                           int nvec, int nvec_pad)
{
  for (int v = blockIdx.x * 256 + threadIdx.x; v < nvec_pad; v += gridDim.x * 256) {
    fx4 x = (v < nvec) ? ((const fx4*)in)[v] : fx4{0.f, 0.f, 0.f, 0.f};
    sx4 h4;
    #pragma unroll
    for (int q = 0; q < 4; q++) h4[q] = (short)f2bf(x[q]);
    ((sx4*)out)[v] = h4;
  }
}

// ---------------------------------------------------------------------------
// Plain-bf16 MFMA GEMM: C[M,N] = A[M,K] @ B[N,K]^T, K=768, BK=32,
// 128x128 tile, 4 waves, global_load_lds staging (verified structure).
// MODE 0: qkv epilogue -> q/k/v bf16 [B,H,N,hd] (bias + 0.125 scale on q)
// MODE 1: proj epilogue -> out fp32 (+bias)
// ---------------------------------------------------------------------------
template<int NT, int MODE>
__global__ __launch_bounds__(256, 2)
void gemm_bf16_kernel(const unsigned short* __restrict__ A,
                      const unsigned short* __restrict__ B,
                      const float* __restrict__ bias0, const float* __restrict__ bias1,
                      unsigned short* __restrict__ qb, unsigned short* __restrict__ kb,
                      unsigned short* __restrict__ vb, float* __restrict__ outp)
{
  __shared__ unsigned short At[128 * 32];
  __shared__ unsigned short Bt[128 * 32];

  const int t  = threadIdx.x;
  const int w  = t >> 6, l = t & 63;
  const int wr = w >> 1, wc = w & 1;
  const int fr = l & 15, g = l >> 4;
  const int bm = blockIdx.x / NT, bn = blockIdx.x % NT;

  const int r_issue = l >> 2;
  const int c_us    = (l & 3) * 8;

  fx4 acc[4][4];
  #pragma unroll
  for (int i = 0; i < 4; i++)
    #pragma unroll
    for (int j = 0; j < 4; j++) acc[i][j] = fx4{0.f, 0.f, 0.f, 0.f};

  #pragma unroll 1
  for (int kt = 0; kt < 24; kt++) {
    const int k0 = kt * 32;

    __syncthreads();
    #pragma unroll
    for (int e2 = 0; e2 < 2; e2++) {
      int e = w * 2 + e2;
      int arow = bm * 128 + e * 16 + r_issue;
      gload16(A + (size_t)arow * KDIM + k0 + c_us, &At[e * 512]);
      int brow = bn * 128 + e * 16 + r_issue;
      gload16(B + (size_t)brow * KDIM + k0 + c_us, &Bt[e * 512]);
    }
    __syncthreads();

    bfx8 fa[4], fb[4];
    #pragma unroll
    for (int i = 0; i < 4; i++)
      fa[i] = *(const bfx8*)&At[(wr * 64 + i * 16 + fr) * 32 + g * 8];
    #pragma unroll
    for (int j = 0; j < 4; j++)
      fb[j] = *(const bfx8*)&Bt[(wc * 64 + j * 16 + fr) * 32 + g * 8];
    #pragma unroll
    for (int i = 0; i < 4; i++)
      #pragma unroll
      for (int j = 0; j < 4; j++)
        acc[i][j] = __builtin_amdgcn_mfma_f32_16x16x32_bf16(fa[i], fb[j], acc[i][j], 0, 0, 0);
  }

  // epilogue: within frag, row = 4*(l>>4)+reg, col = l&15 (verified layout)
  #pragma unroll
  for (int i = 0; i < 4; i++) {
    #pragma unroll
    for (int j = 0; j < 4; j++) {
      #pragma unroll
      for (int r = 0; r < 4; r++) {
        int row = bm * 128 + wr * 64 + i * 16 + g * 4 + r;
        int col = bn * 128 + wc * 64 + j * 16 + fr;
        if (row >= MROWS) continue;
        float v = acc[i][j][r];
        if (MODE == 0) {
          int which = col / 768;
          int hh = (col >> 6) % 12;
          int d  = col & 63;
          int b  = row / NTOK, n = row % NTOK;
          size_t o = (((size_t)(b * NH + hh)) * NTOK + n) * HD + d;
          if (which == 0)      qb[o] = f2bf((v + bias0[col]) * 0.125f);
          else if (which == 1) kb[o] = f2bf(v);
          else                 vb[o] = f2bf(v + bias1[col - 1536]);
        } else {
          outp[(size_t)row * 768 + col] = v + bias0[col];
        }
      }
    }
  }
}

// ---------------------------------------------------------------------------
// MFMA attention (verified round-7 structure; q/k/v now bf16 in, out bf16).
// Block = (b, h, qt 64-row q-tile); 4 waves; wave w owns q-rows w*16..+15.
// ---------------------------------------------------------------------------
__global__ __launch_bounds__(256)
void attn_mfma_kernel(const unsigned short* __restrict__ qf,
                      const unsigned short* __restrict__ kf,
                      const unsigned short* __restrict__ vf,
                      const float* __restrict__ rpb,
                      unsigned short* __restrict__ of)
{
  __shared__ union {
    struct { short Qb[64 * 72]; short Kb[224 * 72]; } s;
    struct { short Pb[64 * 232]; short Vt[64 * 232]; } p;
  } u;

  const int t  = threadIdx.x;
  const int w  = t >> 6, l = t & 63;
  const int fr = l & 15, g = l >> 4;
  const int bx = blockIdx.x;
  const int b  = bx / (NH * 4);
  const int h  = (bx / 4) % NH;
  const int qt = bx & 3;
  const size_t base = ((size_t)(b * NH + h)) * NTOK * HD;
  const unsigned short* qg = qf + base;
  const unsigned short* kg = kf + base;
  const unsigned short* vg = vf + base;
  const float* rhb = rpb + (size_t)h * (NTOK * NTOK);

  // ---- stage Q (64 rows) and K (224 rows, zero-padded), stride 72
  {
    const int rr = t >> 3, c8 = (t & 7) * 8;
    const bfx8 z8 = bfx8{0,0,0,0,0,0,0,0};
    #pragma unroll
    for (int p = 0; p < 2; p++) {
      int r = p * 32 + rr;
      int qrow = qt * 64 + r;
      bfx8 o8 = (qrow < NTOK) ? *(const bfx8*)(qg + (size_t)qrow * HD + c8) : z8;
      *(bfx8*)&u.s.Qb[r * 72 + c8] = o8;
    }
    #pragma unroll
    for (int p = 0; p < 7; p++) {
      int r = p * 32 + rr;
      bfx8 o8 = (r < NTOK) ? *(const bfx8*)(kg + (size_t)r * HD + c8) : z8;
      *(bfx8*)&u.s.Kb[r * 72 + c8] = o8;
    }
  }
  __syncthreads();

  // ---- QK^T
  bfx8 aq0 = *(const bfx8*)&u.s.Qb[(w * 16 + fr) * 72 + g * 8];
  bfx8 aq1 = *(const bfx8*)&u.s.Qb[(w * 16 + fr) * 72 + 32 + g * 8];
  fx4 sc[14];
  #pragma unroll
  for (int j = 0; j < 14; j++) sc[j] = fx4{0.f, 0.f, 0.f, 0.f};
  #pragma unroll
  for (int j = 0; j < 14; j++) {
    bfx8 k0 = *(const bfx8*)&u.s.Kb[(j * 16 + fr) * 72 + g * 8];
    bfx8 k1 = *(const bfx8*)&u.s.Kb[(j * 16 + fr) * 72 + 32 + g * 8];
    sc[j] = __builtin_amdgcn_mfma_f32_16x16x32_bf16(aq0, k0, sc[j], 0, 0, 0);
    sc[j] = __builtin_amdgcn_mfma_f32_16x16x32_bf16(aq1, k1, sc[j], 0, 0, 0);
  }

  // ---- rpb + key mask
  #pragma unroll
  for (int j = 0; j < 14; j++) {
    int key = j * 16 + fr;
    if (key < NTOK) {
      #pragma unroll
      for (int r = 0; r < 4; r++) {
        int qrow = qt * 64 + w * 16 + g * 4 + r;
        if (qrow < NTOK) sc[j][r] += rhb[qrow * NTOK + key];
      }
    } else {
      #pragma unroll
      for (int r = 0; r < 4; r++) sc[j][r] = -1e30f;
    }
  }

  // ---- softmax per row (16-lane fr group); unnormalized exp + inv4[r]
  float inv4[4];
  #pragma unroll
  for (int r = 0; r < 4; r++) {
    float m = sc[0][r];
    #pragma unroll
    for (int j = 1; j < 14; j++) m = fmaxf(m, sc[j][r]);
    #pragma unroll
    for (int off = 1; off < 16; off <<= 1) m = fmaxf(m, __shfl_xor(m, off));
    float sum = 0.f;
    #pragma unroll
    for (int j = 0; j < 14; j++) {
      float e = __expf(sc[j][r] - m);
      sc[j][r] = e; sum += e;
    }
    #pragma unroll
    for (int off = 1; off < 16; off <<= 1) sum += __shfl_xor(sum, off);
    inv4[r] = 1.0f / sum;
  }

  __syncthreads();   // B1: Qb/Kb reads complete -> union reuse safe

  // ---- P (unnormalized bf16) + V transposed
  #pragma unroll
  for (int j = 0; j < 14; j++) {
    int key = j * 16 + fr;
    #pragma unroll
    for (int r = 0; r < 4; r++)
      u.p.Pb[(w * 16 + g * 4 + r) * 232 + key] = (short)f2bf(sc[j][r]);
  }
  #pragma unroll
  for (int rep = 0; rep < 14; rep++) {
    int task = rep * 256 + t;
    int m = task >> 4, dg = task & 15;
    sx4 v4 = (m < NTOK) ? *(const sx4*)(vg + (size_t)m * HD + dg * 4)
                        : sx4{0, 0, 0, 0};
    #pragma unroll
    for (int q2 = 0; q2 < 4; q2++)
      u.p.Vt[(dg * 4 + q2) * 232 + m] = v4[q2];
  }
  __syncthreads();   // B2: P and Vt staged

  // ---- PV
  fx4 o2[4];
  #pragma unroll
  for (int j = 0; j < 4; j++) o2[j] = fx4{0.f, 0.f, 0.f, 0.f};
  #pragma unroll
  for (int kc = 0; kc < 7; kc++) {
    bfx8 pa = *(const bfx8*)&u.p.Pb[(w * 16 + fr) * 232 + kc * 32 + g * 8];
    #pragma unroll
    for (int j = 0; j < 4; j++) {
      bfx8 vb = *(const bfx8*)&u.p.Vt[(j * 16 + fr) * 232 + kc * 32 + g * 8];
      o2[j] = __builtin_amdgcn_mfma_f32_16x16x32_bf16(pa, vb, o2[j], 0, 0, 0);
    }
  }

  // ---- normalize + store bf16: q-row w*16+g*4+r, d = j*16+fr
  #pragma unroll
  for (int r = 0; r < 4; r++) {
    int qrow = qt * 64 + w * 16 + g * 4 + r;
    if (qrow < NTOK) {
      float inv = inv4[r];
      #pragma unroll
      for (int j = 0; j < 4; j++)
        of[((size_t)(b * NTOK + qrow)) * 768 + h * 64 + j * 16 + fr]
            = f2bf(o2[j][r] * inv);
    }
  }
}

// ---------------------------------------------------------------------------
extern "C" void kernel_launch(void* const* d_in, const int* in_sizes, int n_in,
                              void* d_out, int out_size, void* d_ws, size_t ws_size,
                              hipStream_t stream)
{
  const float* x      = (const float*)d_in[0];
  const float* qkv_w  = (const float*)d_in[1];
  const float* q_bias = (const float*)d_in[2];
  const float* v_bias = (const float*)d_in[3];
  const float* proj_w = (const float*)d_in[4];
  const float* proj_b = (const float*)d_in[5];
  const float* rpb_h  = (const float*)d_in[6];
  const float* rpb_w  = (const float*)d_in[7];
  const int*   h_idx  = (const int*)d_in[8];
  const int*   w_idx  = (const int*)d_in[9];
  float* out = (float*)d_out;

  char* ws = (char*)d_ws;
  size_t off = 0;
  auto alloc = [&](size_t bytes) { size_t o = off; off += (bytes + 255) & ~(size_t)255; return o; };

  const size_t QKV_ELEMS = (size_t)BATCH * NH * NTOK * HD;
  unsigned short* Axb = (unsigned short*)(ws + alloc((size_t)MPAD * KDIM * 2));
  unsigned short* Bqb = (unsigned short*)(ws + alloc((size_t)2304 * KDIM * 2));
  unsigned short* Bpb = (unsigned short*)(ws + alloc((size_t)768 * KDIM * 2));
  unsigned short* qb  = (unsigned short*)(ws + alloc(QKV_ELEMS * 2));
  unsigned short* kb  = (unsigned short*)(ws + alloc(QKV_ELEMS * 2));
  unsigned short* vb  = (unsigned short*)(ws + alloc(QKV_ELEMS * 2));
  float*          rpb = (float*)(ws + alloc((size_t)NH * NTOK * NTOK * 4));
  unsigned short* ofb = (unsigned short*)(ws + alloc((size_t)MPAD * KDIM * 2));
  (void)ws_size; (void)in_sizes; (void)n_in; (void)out_size;

  const int nvec_x  = MROWS * KDIM / 4;
  const int nvec_xp = MPAD * KDIM / 4;

  // 1) convert inputs to bf16; rpb table; zero pad rows of attn-out buffer
  cvt_kernel<<<2048, 256, 0, stream>>>(x, Axb, nvec_x, nvec_xp);
  cvt_kernel<<<1024, 256, 0, stream>>>(qkv_w, Bqb, 2304 * KDIM / 4, 2304 * KDIM / 4);
  cvt_kernel<<<512, 256, 0, stream>>>(proj_w, Bpb, 768 * KDIM / 4, 768 * KDIM / 4);
  {
    int total = NH * NTOK * NTOK;
    rpb_kernel<<<(total + 255) / 256, 256, 0, stream>>>(rpb_h, rpb_w, h_idx, w_idx, rpb);
  }
  hipMemsetAsync(ofb + (size_t)MROWS * KDIM, 0,
                 (size_t)(MPAD - MROWS) * KDIM * 2, stream);
  // 2) qkv GEMM: 99 x 18 tiles (128x128), bf16 -> q/k/v bf16
  gemm_bf16_kernel<18, 0><<<99 * 18, 256, 0, stream>>>(
      Axb, Bqb, q_bias, v_bias, qb, kb, vb, nullptr);
  // 3) MFMA attention -> ofb bf16
  attn_mfma_kernel<<<BATCH * NH * 4, 256, 0, stream>>>(qb, kb, vb, rpb, ofb);
  // 4) proj GEMM: 99 x 6 tiles -> out fp32
  gemm_bf16_kernel<6, 1><<<99 * 6, 256, 0, stream>>>(
      ofb, Bpb, proj_b, nullptr, nullptr, nullptr, nullptr, out);
}

// Round 10
// 239.365 us; speedup vs baseline: 2.2190x; 1.1932x over previous
//
#include <hip/hip_runtime.h>
#include <hip/hip_bf16.h>
#include <cstdint>
#include <cstddef>

using fx4  = __attribute__((ext_vector_type(4))) float;
using bfx8 = __attribute__((ext_vector_type(8))) short;
using sx4  = __attribute__((ext_vector_type(4))) short;

#define DEV __device__ __forceinline__

static constexpr int BATCH = 64;
static constexpr int NTOK  = 197;
static constexpr int NH    = 12;
static constexpr int HD    = 64;
static constexpr int MROWS = BATCH * NTOK;   // 12608
static constexpr int MPAD  = 12800;          // covers 99*128 = 12672
static constexpr int KDIM  = 768;

DEV unsigned short f2bf(float f) {
  unsigned u = __builtin_bit_cast(unsigned, f);
  u += 0x7FFFu + ((u >> 16) & 1u);
  return (unsigned short)(u >> 16);
}

DEV void gload16(const unsigned short* g, unsigned short* l) {
  __builtin_amdgcn_global_load_lds(
      (const __attribute__((address_space(1))) unsigned int*)g,
      (__attribute__((address_space(3))) unsigned int*)l, 16, 0, 0);
}

// Bijective XCD-aware block remap (m204): blocks dispatched round-robin to
// XCDs (hw id % 8) receive CONTIGUOUS logical ids, so panel-sharing
// neighbors stay in one XCD's L2.
DEV int xcd_swizzle(int orig, int nwg) {
  int q = nwg >> 3, r = nwg & 7;
  int xcd = orig & 7, lid = orig >> 3;
  return (xcd < r ? xcd * (q + 1) : r * (q + 1) + (xcd - r) * q) + lid;
}

// ---------------------------------------------------------------------------
// rpb[h][i][j] = rpb_high[h_index[i,j], h] + rpb_width[w_index[i,j], h]
// ---------------------------------------------------------------------------
__global__ void rpb_kernel(const float* __restrict__ rh, const float* __restrict__ rw,
                           const int* __restrict__ hidx, const int* __restrict__ widx,
                           float* __restrict__ rpb)
{
  int e = blockIdx.x * 256 + threadIdx.x;
  const int NN = NTOK * NTOK;
  if (e >= NH * NN) return;
  int h = e / NN, ij = e % NN;
  rpb[e] = rh[hidx[ij] * NH + h] + rw[widx[ij] * NH + h];
}

// ---------------------------------------------------------------------------
// Elementwise fp32 -> bf16. Pads [nvec, nvec_pad) with zeros. (fx4 granules)
// ---------------------------------------------------------------------------
__global__ void cvt_kernel(const float* __restrict__ in,
                           unsigned short* __restrict__ out,
                           int nvec, int nvec_pad)
{
  for (int v = blockIdx.x * 256 + threadIdx.x; v < nvec_pad; v += gridDim.x * 256) {
    fx4 x = (v < nvec) ? ((const fx4*)in)[v] : fx4{0.f, 0.f, 0.f, 0.f};
    sx4 h4;
    #pragma unroll
    for (int q = 0; q < 4; q++) h4[q] = (short)f2bf(x[q]);
    ((sx4*)out)[v] = h4;
  }
}

// ---------------------------------------------------------------------------
// Plain-bf16 MFMA GEMM: C[M,N] = A[M,K] @ B[N,K]^T, K=768, BK=32,
// 128x128 tile, 4 waves, global_load_lds staging (verified structure).
// MODE 0: qkv epilogue -> q/k/v bf16 [B,H,N,hd] (bias + 0.125 scale on q)
// MODE 1: proj epilogue -> out fp32 (+bias)
// ---------------------------------------------------------------------------
template<int NT, int MODE>
__global__ __launch_bounds__(256, 2)
void gemm_bf16_kernel(const unsigned short* __restrict__ A,
                      const unsigned short* __restrict__ B,
                      const float* __restrict__ bias0, const float* __restrict__ bias1,
                      unsigned short* __restrict__ qb, unsigned short* __restrict__ kb,
                      unsigned short* __restrict__ vb, float* __restrict__ outp)
{
  __shared__ unsigned short At[128 * 32];
  __shared__ unsigned short Bt[128 * 32];

  const int t  = threadIdx.x;
  const int w  = t >> 6, l = t & 63;
  const int wr = w >> 1, wc = w & 1;
  const int fr = l & 15, g = l >> 4;
  const int bid = xcd_swizzle(blockIdx.x, gridDim.x);
  const int bm = bid / NT, bn = bid % NT;

  const int r_issue = l >> 2;
  const int c_us    = (l & 3) * 8;

  fx4 acc[4][4];
  #pragma unroll
  for (int i = 0; i < 4; i++)
    #pragma unroll
    for (int j = 0; j < 4; j++) acc[i][j] = fx4{0.f, 0.f, 0.f, 0.f};

  #pragma unroll 1
  for (int kt = 0; kt < 24; kt++) {
    const int k0 = kt * 32;

    __syncthreads();
    #pragma unroll
    for (int e2 = 0; e2 < 2; e2++) {
      int e = w * 2 + e2;
      int arow = bm * 128 + e * 16 + r_issue;
      gload16(A + (size_t)arow * KDIM + k0 + c_us, &At[e * 512]);
      int brow = bn * 128 + e * 16 + r_issue;
      gload16(B + (size_t)brow * KDIM + k0 + c_us, &Bt[e * 512]);
    }
    __syncthreads();

    bfx8 fa[4], fb[4];
    #pragma unroll
    for (int i = 0; i < 4; i++)
      fa[i] = *(const bfx8*)&At[(wr * 64 + i * 16 + fr) * 32 + g * 8];
    #pragma unroll
    for (int j = 0; j < 4; j++)
      fb[j] = *(const bfx8*)&Bt[(wc * 64 + j * 16 + fr) * 32 + g * 8];
    #pragma unroll
    for (int i = 0; i < 4; i++)
      #pragma unroll
      for (int j = 0; j < 4; j++)
        acc[i][j] = __builtin_amdgcn_mfma_f32_16x16x32_bf16(fa[i], fb[j], acc[i][j], 0, 0, 0);
  }

  // epilogue: within frag, row = 4*(l>>4)+reg, col = l&15 (verified layout)
  #pragma unroll
  for (int i = 0; i < 4; i++) {
    #pragma unroll
    for (int j = 0; j < 4; j++) {
      #pragma unroll
      for (int r = 0; r < 4; r++) {
        int row = bm * 128 + wr * 64 + i * 16 + g * 4 + r;
        int col = bn * 128 + wc * 64 + j * 16 + fr;
        if (row >= MROWS) continue;
        float v = acc[i][j][r];
        if (MODE == 0) {
          int which = col / 768;
          int hh = (col >> 6) % 12;
          int d  = col & 63;
          int b  = row / NTOK, n = row % NTOK;
          size_t o = (((size_t)(b * NH + hh)) * NTOK + n) * HD + d;
          if (which == 0)      qb[o] = f2bf((v + bias0[col]) * 0.125f);
          else if (which == 1) kb[o] = f2bf(v);
          else                 vb[o] = f2bf(v + bias1[col - 1536]);
        } else {
          outp[(size_t)row * 768 + col] = v + bias0[col];
        }
      }
    }
  }
}

// ---------------------------------------------------------------------------
// MFMA attention (verified round-7/9 structure). Block = (b, h, qt); 4 waves.
// LDS diet: Vt staged in two 32-row halves -> 44.5 KB union -> 3 blocks/CU.
// Vt staging task map puts d-quad in low 3 bits -> 2-way (free) conflicts.
// ---------------------------------------------------------------------------
__global__ __launch_bounds__(256)
void attn_mfma_kernel(const unsigned short* __restrict__ qf,
                      const unsigned short* __restrict__ kf,
                      const unsigned short* __restrict__ vf,
                      const float* __restrict__ rpb,
                      unsigned short* __restrict__ of)
{
  __shared__ union {
    struct { short Qb[64 * 72]; short Kb[224 * 72]; } s;   // 41472 B
    struct { short Pb[64 * 232]; short Vt[32 * 232]; } p;  // 44544 B
  } u;

  const int t  = threadIdx.x;
  const int w  = t >> 6, l = t & 63;
  const int fr = l & 15, g = l >> 4;
  const int bx = xcd_swizzle(blockIdx.x, BATCH * NH * 4);
  const int b  = bx / (NH * 4);
  const int h  = (bx / 4) % NH;
  const int qt = bx & 3;
  const size_t base = ((size_t)(b * NH + h)) * NTOK * HD;
  const unsigned short* qg = qf + base;
  const unsigned short* kg = kf + base;
  const unsigned short* vg = vf + base;
  const float* rhb = rpb + (size_t)h * (NTOK * NTOK);

  // ---- stage Q (64 rows) and K (224 rows, zero-padded), stride 72
  {
    const int rr = t >> 3, c8 = (t & 7) * 8;
    const bfx8 z8 = bfx8{0,0,0,0,0,0,0,0};
    #pragma unroll
    for (int p = 0; p < 2; p++) {
      int r = p * 32 + rr;
      int qrow = qt * 64 + r;
      bfx8 o8 = (qrow < NTOK) ? *(const bfx8*)(qg + (size_t)qrow * HD + c8) : z8;
      *(bfx8*)&u.s.Qb[r * 72 + c8] = o8;
    }
    #pragma unroll
    for (int p = 0; p < 7; p++) {
      int r = p * 32 + rr;
      bfx8 o8 = (r < NTOK) ? *(const bfx8*)(kg + (size_t)r * HD + c8) : z8;
      *(bfx8*)&u.s.Kb[r * 72 + c8] = o8;
    }
  }
  __syncthreads();

  // ---- QK^T
  bfx8 aq0 = *(const bfx8*)&u.s.Qb[(w * 16 + fr) * 72 + g * 8];
  bfx8 aq1 = *(const bfx8*)&u.s.Qb[(w * 16 + fr) * 72 + 32 + g * 8];
  fx4 sc[14];
  #pragma unroll
  for (int j = 0; j < 14; j++) sc[j] = fx4{0.f, 0.f, 0.f, 0.f};
  #pragma unroll
  for (int j = 0; j < 14; j++) {
    bfx8 k0 = *(const bfx8*)&u.s.Kb[(j * 16 + fr) * 72 + g * 8];
    bfx8 k1 = *(const bfx8*)&u.s.Kb[(j * 16 + fr) * 72 + 32 + g * 8];
    sc[j] = __builtin_amdgcn_mfma_f32_16x16x32_bf16(aq0, k0, sc[j], 0, 0, 0);
    sc[j] = __builtin_amdgcn_mfma_f32_16x16x32_bf16(aq1, k1, sc[j], 0, 0, 0);
  }

  // ---- rpb + key mask
  #pragma unroll
  for (int j = 0; j < 14; j++) {
    int key = j * 16 + fr;
    if (key < NTOK) {
      #pragma unroll
      for (int r = 0; r < 4; r++) {
        int qrow = qt * 64 + w * 16 + g * 4 + r;
        if (qrow < NTOK) sc[j][r] += rhb[qrow * NTOK + key];
      }
    } else {
      #pragma unroll
      for (int r = 0; r < 4; r++) sc[j][r] = -1e30f;
    }
  }

  // ---- softmax per row (16-lane fr group); unnormalized exp + inv4[r]
  float inv4[4];
  #pragma unroll
  for (int r = 0; r < 4; r++) {
    float m = sc[0][r];
    #pragma unroll
    for (int j = 1; j < 14; j++) m = fmaxf(m, sc[j][r]);
    #pragma unroll
    for (int off = 1; off < 16; off <<= 1) m = fmaxf(m, __shfl_xor(m, off));
    float sum = 0.f;
    #pragma unroll
    for (int j = 0; j < 14; j++) {
      float e = __expf(sc[j][r] - m);
      sc[j][r] = e; sum += e;
    }
    #pragma unroll
    for (int off = 1; off < 16; off <<= 1) sum += __shfl_xor(sum, off);
    inv4[r] = 1.0f / sum;
  }

  __syncthreads();   // B1: Qb/Kb reads complete -> union reuse safe

  // ---- P (unnormalized bf16)
  #pragma unroll
  for (int j = 0; j < 14; j++) {
    int key = j * 16 + fr;
    #pragma unroll
    for (int r = 0; r < 4; r++)
      u.p.Pb[(w * 16 + g * 4 + r) * 232 + key] = (short)f2bf(sc[j][r]);
  }

  // ---- V-transpose staging, half hf (d in [hf*32, hf*32+32))
  // task map: d-quad in low 3 bits -> per-instruction banks all distinct (2-way).
  auto stageV = [&](int hf) {
    #pragma unroll
    for (int rep = 0; rep < 7; rep++) {
      int task = rep * 256 + t;       // 0..1791
      int m  = task >> 3;             // 0..223
      int dq = task & 7;              // d-quad within half
      sx4 v4 = (m < NTOK) ? *(const sx4*)(vg + (size_t)m * HD + hf * 32 + dq * 4)
                          : sx4{0, 0, 0, 0};
      #pragma unroll
      for (int q2 = 0; q2 < 4; q2++)
        u.p.Vt[(dq * 4 + q2) * 232 + m] = v4[q2];
    }
  };

  fx4 o2[4];
  #pragma unroll
  for (int j = 0; j < 4; j++) o2[j] = fx4{0.f, 0.f, 0.f, 0.f};

  #pragma unroll 1
  for (int hf = 0; hf < 2; hf++) {
    if (hf) __syncthreads();   // B3: half-0 PV reads done before overwrite
    stageV(hf);
    __syncthreads();           // B2/B4: P (+hf half of Vt) staged
    #pragma unroll
    for (int kc = 0; kc < 7; kc++) {
      bfx8 pa = *(const bfx8*)&u.p.Pb[(w * 16 + fr) * 232 + kc * 32 + g * 8];
      #pragma unroll
      for (int jj = 0; jj < 2; jj++) {
        bfx8 vbb = *(const bfx8*)&u.p.Vt[(jj * 16 + fr) * 232 + kc * 32 + g * 8];
        o2[hf * 2 + jj] = __builtin_amdgcn_mfma_f32_16x16x32_bf16(pa, vbb, o2[hf * 2 + jj], 0, 0, 0);
      }
    }
  }

  // ---- normalize + store bf16: q-row w*16+g*4+r, d = j*16+fr
  #pragma unroll
  for (int r = 0; r < 4; r++) {
    int qrow = qt * 64 + w * 16 + g * 4 + r;
    if (qrow < NTOK) {
      float inv = inv4[r];
      #pragma unroll
      for (int j = 0; j < 4; j++)
        of[((size_t)(b * NTOK + qrow)) * 768 + h * 64 + j * 16 + fr]
            = f2bf(o2[j][r] * inv);
    }
  }
}

// ---------------------------------------------------------------------------
extern "C" void kernel_launch(void* const* d_in, const int* in_sizes, int n_in,
                              void* d_out, int out_size, void* d_ws, size_t ws_size,
                              hipStream_t stream)
{
  const float* x      = (const float*)d_in[0];
  const float* qkv_w  = (const float*)d_in[1];
  const float* q_bias = (const float*)d_in[2];
  const float* v_bias = (const float*)d_in[3];
  const float* proj_w = (const float*)d_in[4];
  const float* proj_b = (const float*)d_in[5];
  const float* rpb_h  = (const float*)d_in[6];
  const float* rpb_w  = (const float*)d_in[7];
  const int*   h_idx  = (const int*)d_in[8];
  const int*   w_idx  = (const int*)d_in[9];
  float* out = (float*)d_out;

  char* ws = (char*)d_ws;
  size_t off = 0;
  auto alloc = [&](size_t bytes) { size_t o = off; off += (bytes + 255) & ~(size_t)255; return o; };

  const size_t QKV_ELEMS = (size_t)BATCH * NH * NTOK * HD;
  unsigned short* Axb = (unsigned short*)(ws + alloc((size_t)MPAD * KDIM * 2));
  unsigned short* Bqb = (unsigned short*)(ws + alloc((size_t)2304 * KDIM * 2));
  unsigned short* Bpb = (unsigned short*)(ws + alloc((size_t)768 * KDIM * 2));
  unsigned short* qb  = (unsigned short*)(ws + alloc(QKV_ELEMS * 2));
  unsigned short* kb  = (unsigned short*)(ws + alloc(QKV_ELEMS * 2));
  unsigned short* vb  = (unsigned short*)(ws + alloc(QKV_ELEMS * 2));
  float*          rpb = (float*)(ws + alloc((size_t)NH * NTOK * NTOK * 4));
  unsigned short* ofb = (unsigned short*)(ws + alloc((size_t)MPAD * KDIM * 2));
  (void)ws_size; (void)in_sizes; (void)n_in; (void)out_size;

  const int nvec_x  = MROWS * KDIM / 4;
  const int nvec_xp = MPAD * KDIM / 4;

  // 1) convert inputs to bf16; rpb table; zero pad rows of attn-out buffer
  cvt_kernel<<<2048, 256, 0, stream>>>(x, Axb, nvec_x, nvec_xp);
  cvt_kernel<<<1024, 256, 0, stream>>>(qkv_w, Bqb, 2304 * KDIM / 4, 2304 * KDIM / 4);
  cvt_kernel<<<512, 256, 0, stream>>>(proj_w, Bpb, 768 * KDIM / 4, 768 * KDIM / 4);
  {
    int total = NH * NTOK * NTOK;
    rpb_kernel<<<(total + 255) / 256, 256, 0, stream>>>(rpb_h, rpb_w, h_idx, w_idx, rpb);
  }
  hipMemsetAsync(ofb + (size_t)MROWS * KDIM, 0,
                 (size_t)(MPAD - MROWS) * KDIM * 2, stream);
  // 2) qkv GEMM: 99 x 18 tiles (128x128), bf16 -> q/k/v bf16
  gemm_bf16_kernel<18, 0><<<99 * 18, 256, 0, stream>>>(
      Axb, Bqb, q_bias, v_bias, qb, kb, vb, nullptr);
  // 3) MFMA attention -> ofb bf16
  attn_mfma_kernel<<<BATCH * NH * 4, 256, 0, stream>>>(qb, kb, vb, rpb, ofb);
  // 4) proj GEMM: 99 x 6 tiles -> out fp32
  gemm_bf16_kernel<6, 1><<<99 * 6, 256, 0, stream>>>(
      ofb, Bpb, proj_b, nullptr, nullptr, nullptr, nullptr, out);
}